// Round 11
// baseline (799.544 us; speedup 1.0000x reference)
//
#include <hip/hip_runtime.h>
#include <math.h>

#define NCAND 3872
#define CDIM 80
#define KDIM 256
#define HW 10816
#define HM 104
#define NW32 338    // u32 words per mask (10816 = 338*32 exactly)
#define NW64 169    // u64 words per mask
#define TOPN 500
#define MAXO 100
#define NEGS -1e30f

// ---------------- K1: fused prep = point-NMS/score/class + kernel concat ----
__device__ __forceinline__ void level_of(int r, int& g, int& off) {
    if (r < 1600)      { g = 40; off = 0; }
    else if (r < 2896) { g = 36; off = 1600; }
    else if (r < 3472) { g = 24; off = 2896; }
    else if (r < 3728) { g = 16; off = 3472; }
    else               { g = 12; off = 3728; }
}

__global__ void prep_kernel(const float* __restrict__ c0, const float* __restrict__ c1,
                            const float* __restrict__ c2, const float* __restrict__ c3,
                            const float* __restrict__ c4p,
                            const float* __restrict__ k0, const float* __restrict__ k1,
                            const float* __restrict__ k2, const float* __restrict__ k3,
                            const float* __restrict__ k4p,
                            float* __restrict__ scores, int* __restrict__ classes,
                            float* __restrict__ akern) {
    int t = blockIdx.x * blockDim.x + threadIdx.x;   // float4 index for copy
    if (t < 2 * NCAND * (KDIM / 4)) {
        int c4 = t & 63;
        int bn = t >> 6;
        int b = bn / NCAND, n = bn - b * NCAND;
        int g, off; level_of(n, g, off);
        const float* src = (off == 0) ? k0 : (off == 1600) ? k1 : (off == 2896) ? k2
                           : (off == 3472) ? k3 : k4p;
        int local = n - off;
        ((float4*)akern)[(size_t)bn * 64 + c4] =
            ((const float4*)src)[((size_t)b * g * g + local) * 64 + c4];
    }
    if (t < 2 * NCAND) {
        int b = t / NCAND, r = t - b * NCAND;
        int g, off; level_of(r, g, off);
        const float* cate = (off == 0) ? c0 : (off == 1600) ? c1 : (off == 2896) ? c2
                            : (off == 3472) ? c3 : c4p;
        int local = r - off;
        int i = local / g, j = local - i * g;
        const float* base = cate + ((size_t)(b * g + i) * g + j) * CDIM;
        const float* prev = base - CDIM;  // (i, j-1), valid only if j>0
        float best = -1.0f; int bc = 0;
        for (int c = 0; c < CDIM; c++) {
            float x = base[c];
            float m1 = (j > 0) ? prev[c] : -3.4e38f;
            float m2 = (c > 0) ? base[c - 1] : -3.4e38f;
            float m3 = (j > 0 && c > 0) ? prev[c - 1] : -3.4e38f;
            float v = (x >= m1 && x >= m2 && x >= m3) ? x : 0.0f;
            if (v > best) { best = v; bc = c; }
        }
        scores[t] = best;
        classes[t] = bc;
    }
}

// ---------------- K2: GEMM -> bitpacked masks + partial sums ----------------
// R7 structure (the only one that doesn't spill: load->ds_write->barrier->
// compute->barrier), Tm=4 x Tn=8, 256 threads, BM=64, BN=128.
// CHANGE vs R10: BK 32 -> 16. LDS 25.6KB -> 12.8KB so up to 8 blocks/CU
// (32 waves, 100%) can be resident: barrier/load stalls of one block are
// covered by FMA issue from ~7 others. Accumulation order per output is
// unchanged (k ascending) -> bit-identical results (absmax 0).
#define BM 64
#define BN 128
#define BK 16
#define NTB 85     // ceil(10816/128)
#define APAD 68    // As row stride (floats)
#define BPAD 132   // Bs row stride

__global__ __launch_bounds__(256, 2) void gemm_mask_kernel(
    const float* __restrict__ akern, const float* __restrict__ mask_out,
    unsigned int* __restrict__ maskbits, int* __restrict__ pcnt, double* __restrict__ psig) {
    int bhw = blockIdx.x;   // 0..84  (n tile of 128)
    int bmi = blockIdx.y;   // 0..60  (m tile of 64)
    int b   = blockIdx.z;
    int tid = threadIdx.x;            // 0..255
    int tx = tid & 15, ty = tid >> 4; // tx: n-group 0..15, ty: m-group 0..15
    __shared__ float As[BK][APAD];    // transposed A tile [k][m]
    __shared__ float Bs[BK][BPAD];    // B tile [k][n]
    float acc[2][4][4] = {};          // [ni][r][c]
    int m0 = bmi * BM, n0 = bhw * BN;
    const float* Ab = akern + (size_t)b * NCAND * KDIM;
    const float* Bb = mask_out + (size_t)b * KDIM * HW;

    for (int k0 = 0; k0 < KDIM; k0 += BK) {
        // stage A: 64 rows x 4 float4 = 256 chunks, 1 per thread (transpose)
        {
            int row = tid >> 2, c4 = tid & 3;
            int gm = m0 + row;
            float4 v = make_float4(0.f, 0.f, 0.f, 0.f);
            if (gm < NCAND) v = *(const float4*)(Ab + (size_t)gm * KDIM + k0 + c4 * 4);
            int kk = c4 * 4;
            As[kk + 0][row] = v.x; As[kk + 1][row] = v.y;
            As[kk + 2][row] = v.z; As[kk + 3][row] = v.w;
        }
        // stage B: 16 rows x 32 float4 = 512 chunks, 2 per thread
        #pragma unroll
        for (int i = 0; i < 2; i++) {
            int chunk = tid + i * 256;
            int row = chunk >> 5, c4f = chunk & 31;
            int col = n0 + c4f * 4;
            if (col + 3 >= HW) col = n0;   // clamp (last tile only); discarded in epilogue
            float4 v = *(const float4*)(Bb + (size_t)(k0 + row) * HW + col);
            *(float4*)&Bs[row][c4f * 4] = v;
        }
        __syncthreads();
        #pragma unroll
        for (int kk = 0; kk < BK; kk++) {
            float4 a  = *(const float4*)&As[kk][ty * 4];
            float4 b0 = *(const float4*)&Bs[kk][tx * 4];
            float4 b1 = *(const float4*)&Bs[kk][64 + tx * 4];
            float ar[4] = {a.x, a.y, a.z, a.w};
            float br[2][4] = {{b0.x, b0.y, b0.z, b0.w}, {b1.x, b1.y, b1.z, b1.w}};
            #pragma unroll
            for (int ni = 0; ni < 2; ni++)
                #pragma unroll
                for (int r = 0; r < 4; r++)
                    #pragma unroll
                    for (int c = 0; c < 4; c++)
                        acc[ni][r][c] += ar[r] * br[ni][c];
        }
        __syncthreads();
    }
    // epilogue: sigmoid/threshold/bitpack + per-row partial sums (double)
    #pragma unroll
    for (int r = 0; r < 4; r++) {
        int row = ty * 4 + r;
        int gm = m0 + row;
        double s = 0.0; int cnt = 0;
        unsigned int w[4] = {0u, 0u, 0u, 0u};
        #pragma unroll
        for (int ni = 0; ni < 2; ni++) {
            if (n0 + ni * 64 < HW) {   // block-uniform validity of this 64-col half
                unsigned int nb = 0;
                #pragma unroll
                for (int c = 0; c < 4; c++) {
                    float x = acc[ni][r][c];
                    float p = 1.0f / (1.0f + expf(-x));
                    if (p > 0.5f) { nb |= 1u << c; s += (double)p; cnt++; }
                }
                w[ni * 2 + (tx >> 3)] |= nb << ((tx & 7) * 4);
            }
        }
        #pragma unroll
        for (int off = 1; off < 16; off <<= 1) {
            s   += __shfl_xor(s, off);
            cnt += __shfl_xor(cnt, off);
            #pragma unroll
            for (int q = 0; q < 4; q++) w[q] |= __shfl_xor(w[q], off);
        }
        if (tx == 0 && gm < NCAND) {
            size_t o = ((size_t)b * NTB + bhw) * NCAND + gm;  // tile-major
            pcnt[o] = cnt; psig[o] = s;
            size_t mo = ((size_t)b * NCAND + gm) * NW32;
            int wbase = bhw * 4;
            #pragma unroll
            for (int q = 0; q < 4; q++)
                if (wbase + q < NW32) maskbits[mo + wbase + q] = w[q];
        }
    }
}

// ---------------- K3: reduce partials -> candidate score --------------------
__device__ __forceinline__ float stride_of(int n) {
    if (n < 2896) return 8.0f;
    if (n < 3472) return 16.0f;
    return 32.0f;
}
__global__ void reduce_kernel(const int* __restrict__ pcnt, const double* __restrict__ psig,
                              const float* __restrict__ scores, float* __restrict__ msum,
                              float* __restrict__ candsc) {
    int t = blockIdx.x * blockDim.x + threadIdx.x;
    if (t >= 2 * NCAND) return;
    int b = t / NCAND, n = t - b * NCAND;
    int cnt = 0; double s = 0.0;
    size_t base = (size_t)b * NTB * NCAND + n;
    for (int i = 0; i < NTB; i++) {
        cnt += pcnt[base + (size_t)i * NCAND];
        s   += psig[base + (size_t)i * NCAND];
    }
    float ms = (float)cnt;
    msum[t] = ms;
    float sc = scores[t];
    bool valid = (sc > 0.1f) && (ms > stride_of(n));
    float sf = (float)s;
    float msc = sf / fmaxf(ms, 1.0f);
    candsc[t] = valid ? sc * msc : NEGS;
}

// ---------------- K4: top-500 via bitonic sort (matches lax.top_k ties) -----
__global__ __launch_bounds__(1024) void topk_kernel(const float* __restrict__ candsc,
                                                    float* __restrict__ topscore,
                                                    int* __restrict__ topidx) {
    __shared__ unsigned long long keys[4096];
    int b = blockIdx.x;
    const float* cs = candsc + b * NCAND;
    for (int i = threadIdx.x; i < 4096; i += 1024) {
        unsigned long long key = 0ULL;
        if (i < NCAND) {
            unsigned int u = __float_as_uint(cs[i]);
            unsigned int ord = (u >> 31) ? ~u : (u | 0x80000000u);
            key = ((unsigned long long)ord << 32) | (unsigned long long)(0xFFFFFFFFu - (unsigned)i);
        }
        keys[i] = key;
    }
    __syncthreads();
    for (int size = 2; size <= 4096; size <<= 1) {
        for (int stride = size >> 1; stride > 0; stride >>= 1) {
            for (int t = threadIdx.x; t < 2048; t += 1024) {
                int i = ((t / stride) * (stride << 1)) + (t % stride);
                int j = i + stride;
                unsigned long long a = keys[i], c = keys[j];
                bool asc = ((i & size) == 0);
                bool sw = asc ? (a > c) : (a < c);
                if (sw) { keys[i] = c; keys[j] = a; }
            }
            __syncthreads();
        }
    }
    for (int t = threadIdx.x; t < TOPN; t += 1024) {
        unsigned long long key = keys[4095 - t];   // descending
        unsigned int ord = (unsigned int)(key >> 32);
        unsigned int lo = (unsigned int)key;
        unsigned int u = (ord & 0x80000000u) ? (ord & 0x7FFFFFFFu) : ~ord;
        topscore[b * TOPN + t] = __uint_as_float(u);
        topidx[b * TOPN + t] = (int)(0xFFFFFFFFu - lo);
    }
}

// ---------------- K5: gather selected masks/classes/sums; zero comp ---------
__global__ void gather_kernel(const int* __restrict__ topidx, const float* __restrict__ topscore,
                              const int* __restrict__ classes, const float* __restrict__ msum,
                              const unsigned long long* __restrict__ maskbits64,
                              unsigned long long* __restrict__ selmask,
                              int* __restrict__ selclass, float* __restrict__ selsum,
                              float* __restrict__ comp) {
    int t = blockIdx.x, b = blockIdx.y;
    float sc = topscore[b * TOPN + t];
    bool valid = sc > -5e29f;
    int idx = topidx[b * TOPN + t];
    if (threadIdx.x == 0) {
        selclass[b * TOPN + t] = valid ? classes[b * NCAND + idx] : -1;
        selsum[b * TOPN + t] = valid ? msum[b * NCAND + idx] : 0.0f;
        comp[b * TOPN + t] = 0.0f;   // init for diou's atomicMax
    }
    const unsigned long long* src = maskbits64 + ((size_t)b * NCAND + idx) * NW64;
    unsigned long long* dst = selmask + ((size_t)b * TOPN + t) * NW64;
    for (int w = threadIdx.x; w < NW64; w += blockDim.x)
        dst[w] = valid ? src[w] : 0ULL;
}

// ---------------- K6: pairwise IoU*label (upper tri) + column max into comp -
__global__ void diou_kernel(const unsigned long long* __restrict__ selmask,
                            const float* __restrict__ selsum, const int* __restrict__ selclass,
                            float* __restrict__ diou, unsigned int* __restrict__ compu) {
    int t = blockIdx.x * blockDim.x + threadIdx.x;
    if (t >= TOPN * TOPN) return;
    int b = blockIdx.y;
    int i = t / TOPN, k = t - i * TOPN;
    float v = 0.0f;
    if (k > i) {
        const unsigned long long* mi = selmask + ((size_t)b * TOPN + i) * NW64;
        const unsigned long long* mk = selmask + ((size_t)b * TOPN + k) * NW64;
        int inter = 0;
        for (int w = 0; w < NW64; w++) inter += __popcll(mi[w] & mk[w]);
        float fin = (float)inter;
        float uni = selsum[b * TOPN + i] + selsum[b * TOPN + k] - fin;
        float iou = (uni > 0.f) ? fin / uni : 0.0f;
        float label = (selclass[b * TOPN + i] == selclass[b * TOPN + k]) ? 1.0f : 0.0f;
        v = iou * label;
    }
    diou[(size_t)b * TOPN * TOPN + (size_t)i * TOPN + k] = v;
    // comp[b][k] = max_i v ; v >= 0 so float bit pattern is monotone as uint
    if (v > 0.0f) atomicMax(&compu[b * TOPN + k], __float_as_uint(v));
}

// ---------------- K8: coeff + keep (block per column k, double exp) ---------
__global__ __launch_bounds__(256) void coeff_kernel(const float* __restrict__ diou,
                                                    const float* __restrict__ comp,
                                                    const float* __restrict__ topscore,
                                                    int* __restrict__ keep) {
    int k = blockIdx.x, b = blockIdx.y;
    const float* D = diou + (size_t)b * TOPN * TOPN;
    const float* C = comp + b * TOPN;
    float cmin = 3.4e38f;
    for (int i = threadIdx.x; i < TOPN; i += 256) {
        double d = (double)D[(size_t)i * TOPN + k];
        double ci = (double)C[i];
        float r = (float)(exp(-2.0 * d * d) / exp(-2.0 * ci * ci));
        cmin = fminf(cmin, r);
    }
    #pragma unroll
    for (int off = 32; off >= 1; off >>= 1) cmin = fminf(cmin, __shfl_xor(cmin, off));
    __shared__ float red[4];
    if ((threadIdx.x & 63) == 0) red[threadIdx.x >> 6] = cmin;
    __syncthreads();
    if (threadIdx.x == 0) {
        cmin = fminf(fminf(red[0], red[1]), fminf(red[2], red[3]));
        float ts = topscore[b * TOPN + k];
        keep[b * TOPN + k] = ((ts * cmin >= 0.05f) && (ts > -5e29f)) ? 1 : 0;
    }
}

// ---------------- K9: final top-100 (list is already score-sorted) ----------
__global__ void final_kernel(const int* __restrict__ keep, const float* __restrict__ topscore,
                             const int* __restrict__ selclass, const int* __restrict__ topidx,
                             float* __restrict__ out_scores, float* __restrict__ out_classes,
                             int* __restrict__ fcand) {
    int b = blockIdx.x;
    if (threadIdx.x != 0) return;
    int cnt = 0;
    for (int t = 0; t < TOPN && cnt < MAXO; t++) {
        if (keep[b * TOPN + t]) {
            out_scores[b * MAXO + cnt] = topscore[b * TOPN + t];
            out_classes[b * MAXO + cnt] = (float)selclass[b * TOPN + t];
            fcand[b * MAXO + cnt] = topidx[b * TOPN + t];
            cnt++;
        }
    }
    for (; cnt < MAXO; cnt++) {
        out_scores[b * MAXO + cnt] = -1.0f;
        out_classes[b * MAXO + cnt] = -1.0f;
        fcand[b * MAXO + cnt] = -1;
    }
}

// ---- K10: upsampled mask writes (8 stripes/mask; stripe 0 also does bbox) --
__global__ __launch_bounds__(256) void masks_write_kernel(const int* __restrict__ fcand,
                                                          const unsigned int* __restrict__ maskbits,
                                                          float* __restrict__ outm,
                                                          float* __restrict__ outb) {
    int bm = blockIdx.x;          // 0..199
    int s  = blockIdx.y;          // 0..7 stripe (52 output rows each)
    int b = bm / MAXO;
    int cand = fcand[bm];
    int tid = threadIdx.x;
    __shared__ unsigned int wds[NW32];
    for (int w = tid; w < NW32; w += 256)
        wds[w] = (cand >= 0) ? maskbits[((size_t)b * NCAND + cand) * NW32 + w] : 0u;
    __syncthreads();
    float* om = outm + (size_t)bm * 173056;   // 416*416
    int p4base = s * 5408;                    // 52 rows * 104 float4/row
    for (int pp = tid; pp < 5408; pp += 256) {
        int p4 = p4base + pp;
        int y = p4 / HM, lx = p4 - y * HM;
        int lp = (y >> 2) * HM + lx;
        float v = ((wds[lp >> 5] >> (lp & 31)) & 1u) ? 1.0f : 0.0f;
        float4 o; o.x = o.y = o.z = o.w = v;
        ((float4*)om)[p4] = o;
    }
    if (s != 0) return;
    // bbox from low-res mask bits (stripe-0 blocks only; wds already loaded)
    int xmin = HM, xmax = -1, ymin = HM, ymax = -1;
    for (int p = tid; p < HW; p += 256) {
        if ((wds[p >> 5] >> (p & 31)) & 1u) {
            int y = p / HM, x = p - y * HM;
            xmin = min(xmin, x); xmax = max(xmax, x);
            ymin = min(ymin, y); ymax = max(ymax, y);
        }
    }
    __shared__ int r0[256], r1[256], r2[256], r3[256];
    r0[tid] = xmin; r1[tid] = xmax; r2[tid] = ymin; r3[tid] = ymax;
    __syncthreads();
    for (int st = 128; st > 0; st >>= 1) {
        if (tid < st) {
            r0[tid] = min(r0[tid], r0[tid + st]); r1[tid] = max(r1[tid], r1[tid + st]);
            r2[tid] = min(r2[tid], r2[tid + st]); r3[tid] = max(r3[tid], r3[tid + st]);
        }
        __syncthreads();
    }
    if (tid == 0) {
        float b0 = 0.f, b1 = 0.f, b2 = 0.f, b3 = 0.f;
        if (r1[0] >= 0) {   // not empty
            b0 = (float)(r0[0] * 4); b1 = (float)(r2[0] * 4);
            b2 = (float)(r1[0] * 4 + 3); b3 = (float)(r3[0] * 4 + 3);
        }
        outb[bm * 4 + 0] = b0; outb[bm * 4 + 1] = b1;
        outb[bm * 4 + 2] = b2; outb[bm * 4 + 3] = b3;
    }
}

// ---------------- host ------------------------------------------------------
extern "C" void kernel_launch(void* const* d_in, const int* in_sizes, int n_in,
                              void* d_out, int out_size, void* d_ws, size_t ws_size,
                              hipStream_t stream) {
    // setup_inputs() dict order interleaves cate/kernel per level; detect defensively.
    bool interleaved = (in_sizes[1] == 2 * 40 * 40 * 256);
    const float* cate[5]; const float* kout[5];
    for (int l = 0; l < 5; l++) {
        cate[l] = (const float*)d_in[interleaved ? 2 * l : l];
        kout[l] = (const float*)d_in[interleaved ? 2 * l + 1 : 5 + l];
    }
    const float* mask_out = (const float*)d_in[10];

    char* w = (char*)d_ws;
    auto alloc = [&](size_t bytes) { char* p = w; w += (bytes + 255) & ~(size_t)255; return p; };
    float* akern    = (float*)alloc((size_t)2 * NCAND * KDIM * 4);
    float* scores   = (float*)alloc((size_t)2 * NCAND * 4);
    int*   classes  = (int*)  alloc((size_t)2 * NCAND * 4);
    float* msum     = (float*)alloc((size_t)2 * NCAND * 4);
    float* candsc   = (float*)alloc((size_t)2 * NCAND * 4);
    unsigned int* maskbits = (unsigned int*)alloc((size_t)2 * NCAND * NW32 * 4);
    int*    pcnt    = (int*)   alloc((size_t)2 * NTB * NCAND * 4);
    double* psig    = (double*)alloc((size_t)2 * NTB * NCAND * 8);
    float* topscore = (float*)alloc((size_t)2 * TOPN * 4);
    int*   topidx   = (int*)  alloc((size_t)2 * TOPN * 4);
    int*   selclass = (int*)  alloc((size_t)2 * TOPN * 4);
    float* selsum   = (float*)alloc((size_t)2 * TOPN * 4);
    unsigned long long* selmask = (unsigned long long*)alloc((size_t)2 * TOPN * NW64 * 8);
    float* diou     = (float*)alloc((size_t)2 * TOPN * TOPN * 4);
    float* comp     = (float*)alloc((size_t)2 * TOPN * 4);
    int*   keep     = (int*)  alloc((size_t)2 * TOPN * 4);
    int*   fcand    = (int*)  alloc((size_t)2 * MAXO * 4);

    float* out_scores  = (float*)d_out;                 // [2,100]
    float* out_classes = out_scores + 2 * MAXO;         // [2,100]
    float* out_masks   = out_classes + 2 * MAXO;        // [2,100,416,416]
    float* out_boxes   = out_masks + (size_t)2 * MAXO * 173056;  // [2,100,4]

    prep_kernel<<<(2 * NCAND * 64 + 255) / 256, 256, 0, stream>>>(
        cate[0], cate[1], cate[2], cate[3], cate[4],
        kout[0], kout[1], kout[2], kout[3], kout[4],
        scores, classes, akern);
    gemm_mask_kernel<<<dim3(NTB, (NCAND + BM - 1) / BM, 2), 256, 0, stream>>>(
        akern, mask_out, maskbits, pcnt, psig);
    reduce_kernel<<<(2 * NCAND + 255) / 256, 256, 0, stream>>>(pcnt, psig, scores, msum, candsc);
    topk_kernel<<<2, 1024, 0, stream>>>(candsc, topscore, topidx);
    gather_kernel<<<dim3(TOPN, 2), 256, 0, stream>>>(topidx, topscore, classes, msum,
                                                     (const unsigned long long*)maskbits,
                                                     selmask, selclass, selsum, comp);
    diou_kernel<<<dim3((TOPN * TOPN + 255) / 256, 2), 256, 0, stream>>>(
        selmask, selsum, selclass, diou, (unsigned int*)comp);
    coeff_kernel<<<dim3(TOPN, 2), 256, 0, stream>>>(diou, comp, topscore, keep);
    final_kernel<<<2, 64, 0, stream>>>(keep, topscore, selclass, topidx,
                                       out_scores, out_classes, fcand);
    masks_write_kernel<<<dim3(2 * MAXO, 8), 256, 0, stream>>>(fcand, maskbits, out_masks, out_boxes);
}

// Round 12
// 789.312 us; speedup vs baseline: 1.0130x; 1.0130x over previous
//
#include <hip/hip_runtime.h>
#include <math.h>

#define NCAND 3872
#define CDIM 80
#define KDIM 256
#define HW 10816
#define HM 104
#define NW32 338    // u32 words per mask (10816 = 338*32 exactly)
#define NW64 169    // u64 words per mask
#define TOPN 500
#define MAXO 100
#define NEGS -1e30f

// ---------------- K1: fused prep = point-NMS/score/class + kernel concat ----
__device__ __forceinline__ void level_of(int r, int& g, int& off) {
    if (r < 1600)      { g = 40; off = 0; }
    else if (r < 2896) { g = 36; off = 1600; }
    else if (r < 3472) { g = 24; off = 2896; }
    else if (r < 3728) { g = 16; off = 3472; }
    else               { g = 12; off = 3728; }
}

__global__ void prep_kernel(const float* __restrict__ c0, const float* __restrict__ c1,
                            const float* __restrict__ c2, const float* __restrict__ c3,
                            const float* __restrict__ c4p,
                            const float* __restrict__ k0, const float* __restrict__ k1,
                            const float* __restrict__ k2, const float* __restrict__ k3,
                            const float* __restrict__ k4p,
                            float* __restrict__ scores, int* __restrict__ classes,
                            float* __restrict__ akern) {
    int t = blockIdx.x * blockDim.x + threadIdx.x;   // float4 index for copy
    if (t < 2 * NCAND * (KDIM / 4)) {
        int c4 = t & 63;
        int bn = t >> 6;
        int b = bn / NCAND, n = bn - b * NCAND;
        int g, off; level_of(n, g, off);
        const float* src = (off == 0) ? k0 : (off == 1600) ? k1 : (off == 2896) ? k2
                           : (off == 3472) ? k3 : k4p;
        int local = n - off;
        ((float4*)akern)[(size_t)bn * 64 + c4] =
            ((const float4*)src)[((size_t)b * g * g + local) * 64 + c4];
    }
    if (t < 2 * NCAND) {
        int b = t / NCAND, r = t - b * NCAND;
        int g, off; level_of(r, g, off);
        const float* cate = (off == 0) ? c0 : (off == 1600) ? c1 : (off == 2896) ? c2
                            : (off == 3472) ? c3 : c4p;
        int local = r - off;
        int i = local / g, j = local - i * g;
        const float* base = cate + ((size_t)(b * g + i) * g + j) * CDIM;
        const float* prev = base - CDIM;  // (i, j-1), valid only if j>0
        float best = -1.0f; int bc = 0;
        for (int c = 0; c < CDIM; c++) {
            float x = base[c];
            float m1 = (j > 0) ? prev[c] : -3.4e38f;
            float m2 = (c > 0) ? base[c - 1] : -3.4e38f;
            float m3 = (j > 0 && c > 0) ? prev[c - 1] : -3.4e38f;
            float v = (x >= m1 && x >= m2 && x >= m3) ? x : 0.0f;
            if (v > best) { best = v; bc = c; }
        }
        scores[t] = best;
        classes[t] = bc;
    }
}

// ---------------- K2: GEMM -> bitpacked masks + partial sums ----------------
// R11 diagnosis: 4x8 tile is LDS-read-pipe-bound (0.75 B/FLOP -> 622us floor;
// measured 663 regardless of occupancy/BK/conflicts). Lever = reads per FLOP.
// This round: 8x8 tile (0.5 B/FLOP -> ~420us LDS floor) with BK=16 so LDS is
// 16.9KB -> ~5 blocks/CU residency (R5's 8x8/BK=32 was 4-block latency-bound).
// Schedule stays the proven no-spill R7 form: load->ds_write->barrier->
// compute->barrier. Accumulation order per output unchanged -> absmax 0.
#define BM 128
#define BN 128
#define BK 16
#define NTB 85     // ceil(10816/128)
#define APAD 132   // As row stride (floats)
#define BPAD 132   // Bs row stride

__global__ __launch_bounds__(256, 2) void gemm_mask_kernel(
    const float* __restrict__ akern, const float* __restrict__ mask_out,
    unsigned int* __restrict__ maskbits, int* __restrict__ pcnt, double* __restrict__ psig) {
    int bhw = blockIdx.x;   // 0..84  (n tile of 128)
    int bmi = blockIdx.y;   // 0..30  (m tile of 128)
    int b   = blockIdx.z;
    int tid = threadIdx.x;            // 0..255
    int tx = tid & 15, ty = tid >> 4; // tx: n-group, ty: m-group
    __shared__ float As[BK][APAD];    // transposed A tile [k][m]
    __shared__ float Bs[BK][BPAD];    // B tile [k][n]
    float acc[2][2][4][4] = {};       // [mi][ni][r][c]
    int m0 = bmi * BM, n0 = bhw * BN;
    const float* Ab = akern + (size_t)b * NCAND * KDIM;
    const float* Bb = mask_out + (size_t)b * KDIM * HW;

    for (int k0 = 0; k0 < KDIM; k0 += BK) {
        // stage A: 128 rows x 4 float4 = 512 chunks, 2 per thread (transpose)
        #pragma unroll
        for (int i = 0; i < 2; i++) {
            int chunk = tid + i * 256;
            int row = chunk >> 2, c4 = chunk & 3;
            int gm = m0 + row;
            float4 v = make_float4(0.f, 0.f, 0.f, 0.f);
            if (gm < NCAND) v = *(const float4*)(Ab + (size_t)gm * KDIM + k0 + c4 * 4);
            int kk = c4 * 4;
            As[kk + 0][row] = v.x; As[kk + 1][row] = v.y;
            As[kk + 2][row] = v.z; As[kk + 3][row] = v.w;
        }
        // stage B: 16 rows x 32 float4 = 512 chunks, 2 per thread
        #pragma unroll
        for (int i = 0; i < 2; i++) {
            int chunk = tid + i * 256;
            int row = chunk >> 5, c4f = chunk & 31;
            int col = n0 + c4f * 4;
            if (col + 3 >= HW) col = n0;   // clamp (last tile only); discarded in epilogue
            float4 v = *(const float4*)(Bb + (size_t)(k0 + row) * HW + col);
            *(float4*)&Bs[row][c4f * 4] = v;
        }
        __syncthreads();
        #pragma unroll
        for (int kk = 0; kk < BK; kk++) {
            float4 a0 = *(const float4*)&As[kk][ty * 4];
            float4 a1 = *(const float4*)&As[kk][64 + ty * 4];
            float4 b0 = *(const float4*)&Bs[kk][tx * 4];
            float4 b1 = *(const float4*)&Bs[kk][64 + tx * 4];
            float ar[2][4] = {{a0.x, a0.y, a0.z, a0.w}, {a1.x, a1.y, a1.z, a1.w}};
            float br[2][4] = {{b0.x, b0.y, b0.z, b0.w}, {b1.x, b1.y, b1.z, b1.w}};
            #pragma unroll
            for (int mi = 0; mi < 2; mi++)
                #pragma unroll
                for (int r = 0; r < 4; r++)
                    #pragma unroll
                    for (int ni = 0; ni < 2; ni++)
                        #pragma unroll
                        for (int c = 0; c < 4; c++)
                            acc[mi][ni][r][c] += ar[mi][r] * br[ni][c];
        }
        __syncthreads();
    }
    // epilogue: sigmoid/threshold/bitpack + per-row partial sums (double)
    #pragma unroll
    for (int mi = 0; mi < 2; mi++) {
        #pragma unroll
        for (int r = 0; r < 4; r++) {
            int row = mi * 64 + ty * 4 + r;
            int gm = m0 + row;
            double s = 0.0; int cnt = 0;
            unsigned int w[4] = {0u, 0u, 0u, 0u};
            #pragma unroll
            for (int ni = 0; ni < 2; ni++) {
                if (n0 + ni * 64 < HW) {   // block-uniform validity of this 64-col half
                    unsigned int nb = 0;
                    #pragma unroll
                    for (int c = 0; c < 4; c++) {
                        float x = acc[mi][ni][r][c];
                        float p = 1.0f / (1.0f + expf(-x));
                        if (p > 0.5f) { nb |= 1u << c; s += (double)p; cnt++; }
                    }
                    w[ni * 2 + (tx >> 3)] |= nb << ((tx & 7) * 4);
                }
            }
            #pragma unroll
            for (int off = 1; off < 16; off <<= 1) {
                s   += __shfl_xor(s, off);
                cnt += __shfl_xor(cnt, off);
                #pragma unroll
                for (int q = 0; q < 4; q++) w[q] |= __shfl_xor(w[q], off);
            }
            if (tx == 0 && gm < NCAND) {
                size_t o = ((size_t)b * NTB + bhw) * NCAND + gm;  // tile-major
                pcnt[o] = cnt; psig[o] = s;
                size_t mo = ((size_t)b * NCAND + gm) * NW32;
                int wbase = bhw * 4;
                #pragma unroll
                for (int q = 0; q < 4; q++)
                    if (wbase + q < NW32) maskbits[mo + wbase + q] = w[q];
            }
        }
    }
}

// ---------------- K3: reduce partials -> candidate score --------------------
__device__ __forceinline__ float stride_of(int n) {
    if (n < 2896) return 8.0f;
    if (n < 3472) return 16.0f;
    return 32.0f;
}
__global__ void reduce_kernel(const int* __restrict__ pcnt, const double* __restrict__ psig,
                              const float* __restrict__ scores, float* __restrict__ msum,
                              float* __restrict__ candsc) {
    int t = blockIdx.x * blockDim.x + threadIdx.x;
    if (t >= 2 * NCAND) return;
    int b = t / NCAND, n = t - b * NCAND;
    int cnt = 0; double s = 0.0;
    size_t base = (size_t)b * NTB * NCAND + n;
    for (int i = 0; i < NTB; i++) {
        cnt += pcnt[base + (size_t)i * NCAND];
        s   += psig[base + (size_t)i * NCAND];
    }
    float ms = (float)cnt;
    msum[t] = ms;
    float sc = scores[t];
    bool valid = (sc > 0.1f) && (ms > stride_of(n));
    float sf = (float)s;
    float msc = sf / fmaxf(ms, 1.0f);
    candsc[t] = valid ? sc * msc : NEGS;
}

// ---------------- K4: top-500 via bitonic sort (matches lax.top_k ties) -----
__global__ __launch_bounds__(1024) void topk_kernel(const float* __restrict__ candsc,
                                                    float* __restrict__ topscore,
                                                    int* __restrict__ topidx) {
    __shared__ unsigned long long keys[4096];
    int b = blockIdx.x;
    const float* cs = candsc + b * NCAND;
    for (int i = threadIdx.x; i < 4096; i += 1024) {
        unsigned long long key = 0ULL;
        if (i < NCAND) {
            unsigned int u = __float_as_uint(cs[i]);
            unsigned int ord = (u >> 31) ? ~u : (u | 0x80000000u);
            key = ((unsigned long long)ord << 32) | (unsigned long long)(0xFFFFFFFFu - (unsigned)i);
        }
        keys[i] = key;
    }
    __syncthreads();
    for (int size = 2; size <= 4096; size <<= 1) {
        for (int stride = size >> 1; stride > 0; stride >>= 1) {
            for (int t = threadIdx.x; t < 2048; t += 1024) {
                int i = ((t / stride) * (stride << 1)) + (t % stride);
                int j = i + stride;
                unsigned long long a = keys[i], c = keys[j];
                bool asc = ((i & size) == 0);
                bool sw = asc ? (a > c) : (a < c);
                if (sw) { keys[i] = c; keys[j] = a; }
            }
            __syncthreads();
        }
    }
    for (int t = threadIdx.x; t < TOPN; t += 1024) {
        unsigned long long key = keys[4095 - t];   // descending
        unsigned int ord = (unsigned int)(key >> 32);
        unsigned int lo = (unsigned int)key;
        unsigned int u = (ord & 0x80000000u) ? (ord & 0x7FFFFFFFu) : ~ord;
        topscore[b * TOPN + t] = __uint_as_float(u);
        topidx[b * TOPN + t] = (int)(0xFFFFFFFFu - lo);
    }
}

// ---------------- K5: gather selected masks/classes/sums; zero comp ---------
__global__ void gather_kernel(const int* __restrict__ topidx, const float* __restrict__ topscore,
                              const int* __restrict__ classes, const float* __restrict__ msum,
                              const unsigned long long* __restrict__ maskbits64,
                              unsigned long long* __restrict__ selmask,
                              int* __restrict__ selclass, float* __restrict__ selsum,
                              float* __restrict__ comp) {
    int t = blockIdx.x, b = blockIdx.y;
    float sc = topscore[b * TOPN + t];
    bool valid = sc > -5e29f;
    int idx = topidx[b * TOPN + t];
    if (threadIdx.x == 0) {
        selclass[b * TOPN + t] = valid ? classes[b * NCAND + idx] : -1;
        selsum[b * TOPN + t] = valid ? msum[b * NCAND + idx] : 0.0f;
        comp[b * TOPN + t] = 0.0f;   // init for diou's atomicMax
    }
    const unsigned long long* src = maskbits64 + ((size_t)b * NCAND + idx) * NW64;
    unsigned long long* dst = selmask + ((size_t)b * TOPN + t) * NW64;
    for (int w = threadIdx.x; w < NW64; w += blockDim.x)
        dst[w] = valid ? src[w] : 0ULL;
}

// ---------------- K6: pairwise IoU*label (upper tri) + column max into comp -
__global__ void diou_kernel(const unsigned long long* __restrict__ selmask,
                            const float* __restrict__ selsum, const int* __restrict__ selclass,
                            float* __restrict__ diou, unsigned int* __restrict__ compu) {
    int t = blockIdx.x * blockDim.x + threadIdx.x;
    if (t >= TOPN * TOPN) return;
    int b = blockIdx.y;
    int i = t / TOPN, k = t - i * TOPN;
    float v = 0.0f;
    if (k > i) {
        const unsigned long long* mi = selmask + ((size_t)b * TOPN + i) * NW64;
        const unsigned long long* mk = selmask + ((size_t)b * TOPN + k) * NW64;
        int inter = 0;
        for (int w = 0; w < NW64; w++) inter += __popcll(mi[w] & mk[w]);
        float fin = (float)inter;
        float uni = selsum[b * TOPN + i] + selsum[b * TOPN + k] - fin;
        float iou = (uni > 0.f) ? fin / uni : 0.0f;
        float label = (selclass[b * TOPN + i] == selclass[b * TOPN + k]) ? 1.0f : 0.0f;
        v = iou * label;
    }
    diou[(size_t)b * TOPN * TOPN + (size_t)i * TOPN + k] = v;
    // comp[b][k] = max_i v ; v >= 0 so float bit pattern is monotone as uint
    if (v > 0.0f) atomicMax(&compu[b * TOPN + k], __float_as_uint(v));
}

// ---------------- K8: coeff + keep (block per column k, double exp) ---------
__global__ __launch_bounds__(256) void coeff_kernel(const float* __restrict__ diou,
                                                    const float* __restrict__ comp,
                                                    const float* __restrict__ topscore,
                                                    int* __restrict__ keep) {
    int k = blockIdx.x, b = blockIdx.y;
    const float* D = diou + (size_t)b * TOPN * TOPN;
    const float* C = comp + b * TOPN;
    float cmin = 3.4e38f;
    for (int i = threadIdx.x; i < TOPN; i += 256) {
        double d = (double)D[(size_t)i * TOPN + k];
        double ci = (double)C[i];
        float r = (float)(exp(-2.0 * d * d) / exp(-2.0 * ci * ci));
        cmin = fminf(cmin, r);
    }
    #pragma unroll
    for (int off = 32; off >= 1; off >>= 1) cmin = fminf(cmin, __shfl_xor(cmin, off));
    __shared__ float red[4];
    if ((threadIdx.x & 63) == 0) red[threadIdx.x >> 6] = cmin;
    __syncthreads();
    if (threadIdx.x == 0) {
        cmin = fminf(fminf(red[0], red[1]), fminf(red[2], red[3]));
        float ts = topscore[b * TOPN + k];
        keep[b * TOPN + k] = ((ts * cmin >= 0.05f) && (ts > -5e29f)) ? 1 : 0;
    }
}

// ---------------- K9: final top-100 (list is already score-sorted) ----------
__global__ void final_kernel(const int* __restrict__ keep, const float* __restrict__ topscore,
                             const int* __restrict__ selclass, const int* __restrict__ topidx,
                             float* __restrict__ out_scores, float* __restrict__ out_classes,
                             int* __restrict__ fcand) {
    int b = blockIdx.x;
    if (threadIdx.x != 0) return;
    int cnt = 0;
    for (int t = 0; t < TOPN && cnt < MAXO; t++) {
        if (keep[b * TOPN + t]) {
            out_scores[b * MAXO + cnt] = topscore[b * TOPN + t];
            out_classes[b * MAXO + cnt] = (float)selclass[b * TOPN + t];
            fcand[b * MAXO + cnt] = topidx[b * TOPN + t];
            cnt++;
        }
    }
    for (; cnt < MAXO; cnt++) {
        out_scores[b * MAXO + cnt] = -1.0f;
        out_classes[b * MAXO + cnt] = -1.0f;
        fcand[b * MAXO + cnt] = -1;
    }
}

// ---- K10: upsampled mask writes (8 stripes/mask; stripe 0 also does bbox) --
__global__ __launch_bounds__(256) void masks_write_kernel(const int* __restrict__ fcand,
                                                          const unsigned int* __restrict__ maskbits,
                                                          float* __restrict__ outm,
                                                          float* __restrict__ outb) {
    int bm = blockIdx.x;          // 0..199
    int s  = blockIdx.y;          // 0..7 stripe (52 output rows each)
    int b = bm / MAXO;
    int cand = fcand[bm];
    int tid = threadIdx.x;
    __shared__ unsigned int wds[NW32];
    for (int w = tid; w < NW32; w += 256)
        wds[w] = (cand >= 0) ? maskbits[((size_t)b * NCAND + cand) * NW32 + w] : 0u;
    __syncthreads();
    float* om = outm + (size_t)bm * 173056;   // 416*416
    int p4base = s * 5408;                    // 52 rows * 104 float4/row
    for (int pp = tid; pp < 5408; pp += 256) {
        int p4 = p4base + pp;
        int y = p4 / HM, lx = p4 - y * HM;
        int lp = (y >> 2) * HM + lx;
        float v = ((wds[lp >> 5] >> (lp & 31)) & 1u) ? 1.0f : 0.0f;
        float4 o; o.x = o.y = o.z = o.w = v;
        ((float4*)om)[p4] = o;
    }
    if (s != 0) return;
    // bbox from low-res mask bits (stripe-0 blocks only; wds already loaded)
    int xmin = HM, xmax = -1, ymin = HM, ymax = -1;
    for (int p = tid; p < HW; p += 256) {
        if ((wds[p >> 5] >> (p & 31)) & 1u) {
            int y = p / HM, x = p - y * HM;
            xmin = min(xmin, x); xmax = max(xmax, x);
            ymin = min(ymin, y); ymax = max(ymax, y);
        }
    }
    __shared__ int r0[256], r1[256], r2[256], r3[256];
    r0[tid] = xmin; r1[tid] = xmax; r2[tid] = ymin; r3[tid] = ymax;
    __syncthreads();
    for (int st = 128; st > 0; st >>= 1) {
        if (tid < st) {
            r0[tid] = min(r0[tid], r0[tid + st]); r1[tid] = max(r1[tid], r1[tid + st]);
            r2[tid] = min(r2[tid], r2[tid + st]); r3[tid] = max(r3[tid], r3[tid + st]);
        }
        __syncthreads();
    }
    if (tid == 0) {
        float b0 = 0.f, b1 = 0.f, b2 = 0.f, b3 = 0.f;
        if (r1[0] >= 0) {   // not empty
            b0 = (float)(r0[0] * 4); b1 = (float)(r2[0] * 4);
            b2 = (float)(r1[0] * 4 + 3); b3 = (float)(r3[0] * 4 + 3);
        }
        outb[bm * 4 + 0] = b0; outb[bm * 4 + 1] = b1;
        outb[bm * 4 + 2] = b2; outb[bm * 4 + 3] = b3;
    }
}

// ---------------- host ------------------------------------------------------
extern "C" void kernel_launch(void* const* d_in, const int* in_sizes, int n_in,
                              void* d_out, int out_size, void* d_ws, size_t ws_size,
                              hipStream_t stream) {
    // setup_inputs() dict order interleaves cate/kernel per level; detect defensively.
    bool interleaved = (in_sizes[1] == 2 * 40 * 40 * 256);
    const float* cate[5]; const float* kout[5];
    for (int l = 0; l < 5; l++) {
        cate[l] = (const float*)d_in[interleaved ? 2 * l : l];
        kout[l] = (const float*)d_in[interleaved ? 2 * l + 1 : 5 + l];
    }
    const float* mask_out = (const float*)d_in[10];

    char* w = (char*)d_ws;
    auto alloc = [&](size_t bytes) { char* p = w; w += (bytes + 255) & ~(size_t)255; return p; };
    float* akern    = (float*)alloc((size_t)2 * NCAND * KDIM * 4);
    float* scores   = (float*)alloc((size_t)2 * NCAND * 4);
    int*   classes  = (int*)  alloc((size_t)2 * NCAND * 4);
    float* msum     = (float*)alloc((size_t)2 * NCAND * 4);
    float* candsc   = (float*)alloc((size_t)2 * NCAND * 4);
    unsigned int* maskbits = (unsigned int*)alloc((size_t)2 * NCAND * NW32 * 4);
    int*    pcnt    = (int*)   alloc((size_t)2 * NTB * NCAND * 4);
    double* psig    = (double*)alloc((size_t)2 * NTB * NCAND * 8);
    float* topscore = (float*)alloc((size_t)2 * TOPN * 4);
    int*   topidx   = (int*)  alloc((size_t)2 * TOPN * 4);
    int*   selclass = (int*)  alloc((size_t)2 * TOPN * 4);
    float* selsum   = (float*)alloc((size_t)2 * TOPN * 4);
    unsigned long long* selmask = (unsigned long long*)alloc((size_t)2 * TOPN * NW64 * 8);
    float* diou     = (float*)alloc((size_t)2 * TOPN * TOPN * 4);
    float* comp     = (float*)alloc((size_t)2 * TOPN * 4);
    int*   keep     = (int*)  alloc((size_t)2 * TOPN * 4);
    int*   fcand    = (int*)  alloc((size_t)2 * MAXO * 4);

    float* out_scores  = (float*)d_out;                 // [2,100]
    float* out_classes = out_scores + 2 * MAXO;         // [2,100]
    float* out_masks   = out_classes + 2 * MAXO;        // [2,100,416,416]
    float* out_boxes   = out_masks + (size_t)2 * MAXO * 173056;  // [2,100,4]

    prep_kernel<<<(2 * NCAND * 64 + 255) / 256, 256, 0, stream>>>(
        cate[0], cate[1], cate[2], cate[3], cate[4],
        kout[0], kout[1], kout[2], kout[3], kout[4],
        scores, classes, akern);
    gemm_mask_kernel<<<dim3(NTB, (NCAND + BM - 1) / BM, 2), 256, 0, stream>>>(
        akern, mask_out, maskbits, pcnt, psig);
    reduce_kernel<<<(2 * NCAND + 255) / 256, 256, 0, stream>>>(pcnt, psig, scores, msum, candsc);
    topk_kernel<<<2, 1024, 0, stream>>>(candsc, topscore, topidx);
    gather_kernel<<<dim3(TOPN, 2), 256, 0, stream>>>(topidx, topscore, classes, msum,
                                                     (const unsigned long long*)maskbits,
                                                     selmask, selclass, selsum, comp);
    diou_kernel<<<dim3((TOPN * TOPN + 255) / 256, 2), 256, 0, stream>>>(
        selmask, selsum, selclass, diou, (unsigned int*)comp);
    coeff_kernel<<<dim3(TOPN, 2), 256, 0, stream>>>(diou, comp, topscore, keep);
    final_kernel<<<2, 64, 0, stream>>>(keep, topscore, selclass, topidx,
                                       out_scores, out_classes, fcand);
    masks_write_kernel<<<dim3(2 * MAXO, 8), 256, 0, stream>>>(fcand, maskbits, out_masks, out_boxes);
}